// Round 11
// baseline (579.850 us; speedup 1.0000x reference)
//
#include <hip/hip_runtime.h>
#include <hip/hip_bf16.h>

// N=12288, D=256. Single pass:
//   e=lrelu(u_i+v_j); q=exp2(e*log2e-SHIFT2) masked adj>0 (const shift, scale-free)
//   out_i = coef_i*(q_i@h_po) + 0.5*(adj_i@h_po),  coef_i=0.5*deg_i/denom_i
// fused11 = fused9's proven geometry (BM=48, grid 256 = 1 block/CU, 12 waves =
// 3rg x 2dh x 2kh, XOR-swizzled tiles, gl_lds staging, persistent pointers)
// + T3/T4: 3-buffer depth-2 staging, s_waitcnt vmcnt(8) + raw s_barrier
//   (NEVER vmcnt(0) in main loop; uniform 4 gl_lds + 2 v-loads per wave per
//   step so the count is exact; m135 in-order retirement)
// + v in REGISTERS (fused7-proven; fused9's v-in-LDS regressed an LDS-bound loop)
// + unroll-3 with ONE shared pointer set (fused8 spill post-mortem).

#define NN 12288
#define DD 256
#define BM 48
#define BK 64
#define NSTEPS (NN / BK)   // 192
#define LOG2E 1.44269504f
#define SHIFT2 36.067376f  // 25*log2e

typedef __attribute__((ext_vector_type(8))) short s16x8;
typedef __attribute__((ext_vector_type(4))) float f32x4;

__device__ __forceinline__ unsigned short f2bf(float f) {
  unsigned u = __builtin_bit_cast(unsigned, f);
  u += 0x7FFFu + ((u >> 16) & 1u);
  return (unsigned short)(u >> 16);
}
__device__ __forceinline__ unsigned pack_bf2(float a, float b) {
  unsigned short lo = __builtin_bit_cast(unsigned short, __float2bfloat16(a));
  unsigned short hi = __builtin_bit_cast(unsigned short, __float2bfloat16(b));
  return (unsigned)lo | ((unsigned)hi << 16);
}
__device__ __forceinline__ float exp2_hw(float x) {
  float r;
  asm("v_exp_f32 %0, %1" : "=v"(r) : "v"(x));
  return r;
}
__device__ __forceinline__ void gl_lds16(const void* g, void* l) {
  __builtin_amdgcn_global_load_lds(
      (const __attribute__((address_space(1))) void*)g,
      (__attribute__((address_space(3))) void*)l, 16, 0, 0);
}

// ---------------- prep: u2, v2 (pre-scaled by log2e) ----------------
__global__ __launch_bounds__(256) void prep_uv(
    const float* __restrict__ h_eu, const float* __restrict__ h_po,
    const float* __restrict__ h_lo, const float* __restrict__ a1,
    const float* __restrict__ a2, const float* __restrict__ a3,
    float* __restrict__ u, float* __restrict__ v) {
  const int t = threadIdx.x;
  const int wave = t >> 6, lane = t & 63;
  const int r0 = blockIdx.x * 64;
  for (int rr = 0; rr < 16; ++rr) {
    const int row = r0 + wave * 16 + rr;
    const float* pe = h_eu + (size_t)row * DD;
    const float* pl = h_lo + (size_t)row * DD;
    const float* pp = h_po + (size_t)row * DD;
    float su = 0.f, sv = 0.f;
#pragma unroll
    for (int c = 0; c < 4; ++c) {
      const int d = lane + c * 64;
      su = fmaf(pe[d], a1[d], su);
      su = fmaf(pl[d], a3[d], su);
      sv = fmaf(pp[d], a2[d], sv);
    }
#pragma unroll
    for (int m = 32; m; m >>= 1) {
      su += __shfl_xor(su, m, 64);
      sv += __shfl_xor(sv, m, 64);
    }
    if (lane == 0) { u[row] = su * LOG2E; v[row] = sv * LOG2E; }
  }
}

// ---------------- prep: h_poT (bf16, [D][N]) ----------------
__global__ __launch_bounds__(256) void prep_T(
    const float* __restrict__ hpo, unsigned short* __restrict__ h_poT) {
  const int t = threadIdx.x;
  const int r0 = blockIdx.x * 64;
  unsigned short* dst = h_poT + (size_t)t * NN + r0;
#pragma unroll
  for (int c = 0; c < 16; ++c) {
    unsigned short x0 = f2bf(hpo[(size_t)(r0 + c * 4 + 0) * DD + t]);
    unsigned short x1 = f2bf(hpo[(size_t)(r0 + c * 4 + 1) * DD + t]);
    unsigned short x2 = f2bf(hpo[(size_t)(r0 + c * 4 + 2) * DD + t]);
    unsigned short x3 = f2bf(hpo[(size_t)(r0 + c * 4 + 3) * DD + t]);
    ((uint2*)dst)[c] = make_uint2((unsigned)x0 | ((unsigned)x1 << 16),
                                  (unsigned)x2 | ((unsigned)x3 << 16));
  }
}

// ---------------- fused11 ----------------
__global__ __launch_bounds__(768) void fused11(
    const float* __restrict__ adj, const float* __restrict__ u2,
    const float* __restrict__ v2, const unsigned short* __restrict__ h_poT,
    float* __restrict__ out) {
  __shared__ __align__(16) char sAdj[3][BM * 256];   // 36 KB
  __shared__ __align__(16) char sB[3][DD * 128];     // 96 KB
  __shared__ __align__(16) char sDump[1024];         // dummy-op target
  __shared__ float sq[2][3][16], sa[2][3][16];

  const int t = threadIdx.x;
  const int w = t >> 6, lane = t & 63;
  const int rg = w >> 2;           // 0..2  row-group (16 rows)
  const int dh = (w >> 1) & 1;     // 0..1  D-half (128 cols)
  const int kh = w & 1;            // 0..1  k-slice (32 of 64)
  const int lrow = lane & 15, kgrp = lane >> 4;
  const int i0 = blockIdx.x * BM;
  const int row = i0 + rg * 16 + lrow;
  const float u_r = u2[row];
  const float uc1 = u_r - SHIFT2;
  const float uc2 = fmaf(0.01f, u_r, -SHIFT2);
  const int xr = (lrow & 7) << 4;

  // read-side per-thread constant offsets (fused9-proven)
  const int aOff = (rg * 16 + lrow) * 256;
  const int kA0 = (kh * 128 + kgrp * 32) ^ xr;
  const int kA1 = (kh * 128 + kgrp * 32 + 16) ^ xr;
  const int bOff = (dh * 128 + lrow) * 128 + ((kh * 64 + kgrp * 16) ^ xr);
  const float* vbase = v2 + kh * 32 + kgrp * 8;  // + s*64 per step

  // persistent self-advancing staging source pointers (fused9-proven)
  const char* pAdj = (const char*)(adj + (size_t)(i0 + w * 4 + (lane >> 4)) * NN)
                     + (((lane & 15) ^ ((w & 1) * 4 + (lane >> 4))) << 4);
  const int ko = ((lane & 7) ^ (lane >> 3)) << 4;
  const char* pB0 = (const char*)h_poT + (size_t)(w * 8 + (lane >> 3)) * (NN * 2) + ko;
  const char* pB1 = (const char*)h_poT + (size_t)((w + 12) * 8 + (lane >> 3)) * (NN * 2) + ko;
  const char* pB2 = (const char*)h_poT + (size_t)(((w < 8 ? w + 24 : 7 + 24)) * 8 + (lane >> 3)) * (NN * 2) + ko;
  const int dAdj = w * 1024;
  const int dB0 = w * 1024;
  const int dB1 = (w + 12) * 1024;
  const int dB2 = (w + 24) * 1024;  // only valid for w<8
  const bool hasB2 = (w < 8);

  f32x4 acc1[8] = {};  // q   @ B
  f32x4 acc2[8] = {};  // adj @ B
  float qsum = 0.f, asum = 0.f;

  float4 V0[3], V1[3];  // v pipeline, 3 deep, statically indexed

  // uniform 4 gl_lds per wave per step (waves 8-11: 4th is a dummy L2-hit
  // into sDump -- keeps the per-wave vmcnt count exact for SYNCV8)
#define DO_STAGE(B_)                                                 \
  {                                                                  \
    gl_lds16(pAdj, sAdj[B_] + dAdj); pAdj += 256;                    \
    gl_lds16(pB0, sB[B_] + dB0);     pB0 += 128;                     \
    gl_lds16(pB1, sB[B_] + dB1);     pB1 += 128;                     \
    if (hasB2) { gl_lds16(pB2, sB[B_] + dB2); pB2 += 128; }          \
    else       { gl_lds16(pB2, sDump); }                             \
  }

#define LOAD_V(SLOT_, S_)                         \
  {                                               \
    V0[SLOT_] = *(const float4*)(vbase + (S_)*64);\
    V1[SLOT_] = *(const float4*)(vbase + (S_)*64 + 4); \
  }

#define DO_COMPUTE(B_, VS_)                                                   \
  {                                                                           \
    const char* ab_ = sAdj[B_] + aOff;                                        \
    const f32x4 A0 = *(const f32x4*)(ab_ + kA0);                              \
    const f32x4 A1 = *(const f32x4*)(ab_ + kA1);                              \
    const float af[8] = {A0[0], A0[1], A0[2], A0[3],                          \
                         A1[0], A1[1], A1[2], A1[3]};                         \
    const float vf[8] = {V0[VS_].x, V0[VS_].y, V0[VS_].z, V0[VS_].w,          \
                         V1[VS_].x, V1[VS_].y, V1[VS_].z, V1[VS_].w};         \
    float qv[8];                                                              \
    _Pragma("unroll") for (int e = 0; e < 8; ++e) {                           \
      const float t1 = uc1 + vf[e];                                           \
      const float t2 = fmaf(0.01f, vf[e], uc2);                               \
      float q = exp2_hw(fmaxf(t1, t2));                                       \
      q = (af[e] > 0.f) ? q : 0.f;                                            \
      qsum += q; asum += af[e]; qv[e] = q;                                    \
    }                                                                         \
    unsigned qp[4], ap[4];                                                    \
    _Pragma("unroll") for (int e = 0; e < 4; ++e) {                           \
      qp[e] = pack_bf2(qv[2 * e], qv[2 * e + 1]);                             \
      ap[e] = pack_bf2(af[2 * e], af[2 * e + 1]);                             \
    }                                                                         \
    const s16x8 qa = __builtin_bit_cast(s16x8, *(uint4*)qp);                  \
    const s16x8 aa = __builtin_bit_cast(s16x8, *(uint4*)ap);                  \
    const char* bb_ = sB[B_] + bOff;                                          \
    _Pragma("unroll") for (int dt = 0; dt < 8; ++dt) {                        \
      const s16x8 bb = *(const s16x8*)(bb_ + dt * 2048);                      \
      acc1[dt] = __builtin_amdgcn_mfma_f32_16x16x32_bf16(qa, bb, acc1[dt], 0, 0, 0); \
      acc2[dt] = __builtin_amdgcn_mfma_f32_16x16x32_bf16(aa, bb, acc2[dt], 0, 0, 0); \
    }                                                                         \
  }

  // counted sync: stage(s+1) guaranteed complete, stage(s+2)+v stay in flight
#define SYNCV8 { asm volatile("s_waitcnt vmcnt(8)" ::: "memory"); \
                 __builtin_amdgcn_s_barrier(); }
#define SYNCV0 { asm volatile("s_waitcnt vmcnt(0)" ::: "memory"); \
                 __builtin_amdgcn_s_barrier(); }

  // prologue: stage steps 0,1 (depth 2); v for 0,1
  DO_STAGE(0) LOAD_V(0, 0)
  DO_STAGE(1) LOAD_V(1, 1)
  SYNCV8  // outstanding: v(0)2 + stage(1)4 + v(1)2 = 8 -> stage(0) done

  // main: 63 iters x 3 steps = steps 0..188, staging 2..190
  for (int it = 0; it < 63; ++it) {
    DO_STAGE(2) LOAD_V(2, it * 3 + 2) DO_COMPUTE(0, 0) SYNCV8
    DO_STAGE(0) LOAD_V(0, it * 3 + 3) DO_COMPUTE(1, 1) SYNCV8
    DO_STAGE(1) LOAD_V(1, it * 3 + 4) DO_COMPUTE(2, 2) SYNCV8
  }
  // peel: steps 189,190,191 (stage 191; then drain)
  DO_STAGE(2) LOAD_V(2, 191) DO_COMPUTE(0, 0) SYNCV8
  DO_COMPUTE(1, 1) SYNCV0
  DO_COMPUTE(2, 2)

#undef DO_STAGE
#undef LOAD_V
#undef DO_COMPUTE
#undef SYNCV8
#undef SYNCV0

  // ---- stats: per-row sums (this wave's k-slice) -> LDS ----
  qsum += __shfl_xor(qsum, 16, 64); qsum += __shfl_xor(qsum, 32, 64);
  asum += __shfl_xor(asum, 16, 64); asum += __shfl_xor(asum, 32, 64);
  if (dh == 0 && lane < 16) { sq[kh][rg][lane] = qsum; sa[kh][rg][lane] = asum; }
  __syncthreads();

  // ---- fold coef, reduce over kh via LDS (reuse sB), write out ----
  f32x4 fin[8];
#pragma unroll
  for (int dt = 0; dt < 8; ++dt) {
#pragma unroll
    for (int g = 0; g < 4; ++g) {
      const int rr = kgrp * 4 + g;
      const float qq = sq[0][rg][rr] + sq[1][rg][rr];
      const float aa2 = sa[0][rg][rr] + sa[1][rg][rr];
      const float cfr = qq > 0.f ? 0.5f * aa2 / qq : 0.f;
      fin[dt][g] = cfr * acc1[dt][g] + 0.5f * acc2[dt][g];
    }
  }
  float* red = (float*)sB;  // [(rg*2+dh)*8+dt][lane][4] f32 = 48 KB
  const int rbase = ((rg * 2 + dh) * 8 * 64 + lane) * 4;
  if (kh == 1) {
#pragma unroll
    for (int dt = 0; dt < 8; ++dt) *(f32x4*)&red[rbase + dt * 256] = fin[dt];
  }
  __syncthreads();
  if (kh == 0) {
#pragma unroll
    for (int dt = 0; dt < 8; ++dt) {
      const f32x4 o = *(const f32x4*)&red[rbase + dt * 256];
      const int col = dh * 128 + dt * 16 + lrow;
#pragma unroll
      for (int g = 0; g < 4; ++g)
        out[(size_t)(i0 + rg * 16 + kgrp * 4 + g) * DD + col] = fin[dt][g] + o[g];
    }
  }
}

// ---------------- fallback (small ws): round-2 proven kernel ----------------
__global__ __launch_bounds__(256) void fused_fb(
    const float* __restrict__ adj, const float* __restrict__ u,
    const float* __restrict__ v, const float* __restrict__ hpo,
    float* __restrict__ out) {
#define BMF 32
#define LDA 40
  __shared__ unsigned short qlds[BMF][LDA];
  __shared__ unsigned short alds[BMF][LDA];
  __shared__ unsigned short btf[DD][LDA];
  __shared__ float denom_s[BMF], deg_s[BMF], coef_s[BMF];

  const int t = threadIdx.x;
  const int wave = t >> 6, lane = t & 63;
  const int i0 = blockIdx.x * BMF;
  const int sr = t >> 3;
  const int sc = (t & 7) * 4;
  const float u_r = u[i0 + sr];
  const int d0 = wave * 64;
  const int lrow = lane & 15;
  const int kgrp = lane >> 4;

  f32x4 acc1[2][4] = {};
  f32x4 acc2[2][4] = {};
  float qsum = 0.f, asum = 0.f;

  const float* arow = adj + (size_t)(i0 + sr) * NN + sc;
  float4 a_cur = *(const float4*)(arow);

  constexpr int NSTEP = NN / 32;
  for (int jt = 0; jt < NSTEP; ++jt) {
    const int j = jt * 32;
    float4 a_nxt;
    const bool has_next = (jt + 1 < NSTEP);
    if (has_next) a_nxt = *(const float4*)(arow + j + 32);
    const float4 vv = *(const float4*)(v + j + sc);
    unsigned short qb[4], ab[4];
    {
      const float aa4[4] = {a_cur.x, a_cur.y, a_cur.z, a_cur.w};
      const float vvv[4] = {vv.x, vv.y, vv.z, vv.w};
#pragma unroll
      for (int k = 0; k < 4; ++k) {
        const float a = aa4[k];
        const float s = u_r + vvv[k];
        const float x = fmaxf(s, 0.01f * s);
        const float q = (a > 0.f) ? exp2_hw(x - SHIFT2) : 0.f;
        qsum += q;
        asum += a;
        qb[k] = f2bf(q);
        ab[k] = f2bf(a);
      }
    }
    *(uint2*)&qlds[sr][sc] = make_uint2((unsigned)qb[0] | ((unsigned)qb[1] << 16),
                                        (unsigned)qb[2] | ((unsigned)qb[3] << 16));
    *(uint2*)&alds[sr][sc] = make_uint2((unsigned)ab[0] | ((unsigned)ab[1] << 16),
                                        (unsigned)ab[2] | ((unsigned)ab[3] << 16));
    {
      const int br = t >> 3;
      const float* src = hpo + (size_t)(j + br) * DD;
#pragma unroll
      for (int cc = 0; cc < 8; ++cc) {
        const int c = (t & 7) * 4 + cc * 32;
        const float4 hv = *(const float4*)(src + c);
        btf[c + 0][br] = f2bf(hv.x);
        btf[c + 1][br] = f2bf(hv.y);
        btf[c + 2][br] = f2bf(hv.z);
        btf[c + 3][br] = f2bf(hv.w);
      }
    }
    __syncthreads();

    const s16x8 qa0 = *(const s16x8*)&qlds[lrow][kgrp * 8];
    const s16x8 qa1 = *(const s16x8*)&qlds[16 + lrow][kgrp * 8];
    const s16x8 ad0 = *(const s16x8*)&alds[lrow][kgrp * 8];
    const s16x8 ad1 = *(const s16x8*)&alds[16 + lrow][kgrp * 8];
#pragma unroll
    for (int dt = 0; dt < 4; ++dt) {
      const s16x8 b = *(const s16x8*)&btf[d0 + dt * 16 + lrow][kgrp * 8];
      acc1[0][dt] = __builtin_amdgcn_mfma_f32_16x16x32_bf16(qa0, b, acc1[0][dt], 0, 0, 0);
      acc1[1][dt] = __builtin_amdgcn_mfma_f32_16x16x32_bf16(qa1, b, acc1[1][dt], 0, 0, 0);
      acc2[0][dt] = __builtin_amdgcn_mfma_f32_16x16x32_bf16(ad0, b, acc2[0][dt], 0, 0, 0);
      acc2[1][dt] = __builtin_amdgcn_mfma_f32_16x16x32_bf16(ad1, b, acc2[1][dt], 0, 0, 0);
    }
    __syncthreads();
    if (has_next) a_cur = a_nxt;
  }
#pragma unroll
  for (int m = 1; m <= 4; m <<= 1) {
    qsum += __shfl_xor(qsum, m, 64);
    asum += __shfl_xor(asum, m, 64);
  }
  if ((t & 7) == 0) { denom_s[sr] = qsum; deg_s[sr] = asum; }
  __syncthreads();
  if (t < BMF) {
    const float dn = denom_s[t];
    coef_s[t] = dn > 0.f ? 0.5f * deg_s[t] / dn : 0.f;
  }
  __syncthreads();
#pragma unroll
  for (int f = 0; f < 2; ++f) {
#pragma unroll
    for (int dt = 0; dt < 4; ++dt) {
      const int col = d0 + dt * 16 + lrow;
#pragma unroll
      for (int g = 0; g < 4; ++g) {
        const int r = f * 16 + kgrp * 4 + g;
        out[(size_t)(i0 + r) * DD + col] =
            coef_s[r] * acc1[f][dt][g] + 0.5f * acc2[f][dt][g];
      }
    }
  }
}

extern "C" void kernel_launch(void* const* d_in, const int* in_sizes, int n_in,
                              void* d_out, int out_size, void* d_ws, size_t ws_size,
                              hipStream_t stream) {
  const float* h_eu = (const float*)d_in[0];
  const float* h_po = (const float*)d_in[1];
  const float* h_lo = (const float*)d_in[2];
  const float* adj  = (const float*)d_in[3];
  const float* a1   = (const float*)d_in[4];
  const float* a2   = (const float*)d_in[5];
  const float* a3   = (const float*)d_in[6];
  float* out = (float*)d_out;

  // ws layout: u[N] | v[N] | h_poT[D*N] bf16 = 6,389,760 B
  const size_t need_full = (size_t)2 * NN * 4 + (size_t)NN * DD * 2;
  float* u = (float*)d_ws;
  float* v = u + NN;
  unsigned short* h_poT = (unsigned short*)(v + NN);
  const bool big_ws = ws_size >= need_full;

  prep_uv<<<NN / 64, 256, 0, stream>>>(h_eu, h_po, h_lo, a1, a2, a3, u, v);
  if (big_ws) {
    prep_T<<<NN / 64, 256, 0, stream>>>(h_po, h_poT);
    fused11<<<NN / BM, 768, 0, stream>>>(adj, u, v, h_poT, out);
  } else {
    fused_fb<<<NN / 32, 256, 0, stream>>>(adj, u, v, h_po, out);
  }
}

// Round 12
// 308.546 us; speedup vs baseline: 1.8793x; 1.8793x over previous
//
#include <hip/hip_runtime.h>
#include <hip/hip_bf16.h>

// N=12288, D=256. Single pass:
//   e=lrelu(u_i+v_j); q=exp2(e*log2e-SHIFT2) masked adj>0 (const shift, scale-free)
//   out_i = coef_i*(q_i@h_po) + 0.5*(adj_i@h_po),  coef_i=0.5*deg_i/denom_i
// fused12: WAVE SPECIALIZATION, zero inline asm.
//   16 waves (1024 thr): 12 consumers (fused9's 3rg x 2dh x 2kh compute; LDS-only
//   in-loop -> barrier waits free) + 4 producers (stage buffer s+2 of a triple
//   buffer via global_load_lds; compiler's own vmcnt(0)-at-barrier is the
//   pipeline wait, overlapped with consumer compute). v staged per-buffer.
//   All formulas/swizzles/numerics byte-carried from passing fused7/9.

#define NN 12288
#define DD 256
#define BM 48
#define BK 64
#define NSTEPS (NN / BK)   // 192
#define ADJSZ 12288
#define BOFF 12288
#define VOFF 45056
#define BUFSZ 45312        // adj 12288 + B 32768 + v 256
#define LOG2E 1.44269504f
#define SHIFT2 36.067376f  // 25*log2e

typedef __attribute__((ext_vector_type(8))) short s16x8;
typedef __attribute__((ext_vector_type(4))) float f32x4;

__device__ __forceinline__ unsigned short f2bf(float f) {
  unsigned u = __builtin_bit_cast(unsigned, f);
  u += 0x7FFFu + ((u >> 16) & 1u);
  return (unsigned short)(u >> 16);
}
__device__ __forceinline__ unsigned pack_bf2(float a, float b) {
  unsigned short lo = __builtin_bit_cast(unsigned short, __float2bfloat16(a));
  unsigned short hi = __builtin_bit_cast(unsigned short, __float2bfloat16(b));
  return (unsigned)lo | ((unsigned)hi << 16);
}
__device__ __forceinline__ float exp2_hw(float x) {
  float r;
  asm("v_exp_f32 %0, %1" : "=v"(r) : "v"(x));
  return r;
}
__device__ __forceinline__ void gl_lds16(const void* g, void* l) {
  __builtin_amdgcn_global_load_lds(
      (const __attribute__((address_space(1))) void*)g,
      (__attribute__((address_space(3))) void*)l, 16, 0, 0);
}
__device__ __forceinline__ void gl_lds4(const void* g, void* l) {
  __builtin_amdgcn_global_load_lds(
      (const __attribute__((address_space(1))) void*)g,
      (__attribute__((address_space(3))) void*)l, 4, 0, 0);
}

// ---------------- prep: u2, v2 (pre-scaled by log2e) ----------------
__global__ __launch_bounds__(256) void prep_uv(
    const float* __restrict__ h_eu, const float* __restrict__ h_po,
    const float* __restrict__ h_lo, const float* __restrict__ a1,
    const float* __restrict__ a2, const float* __restrict__ a3,
    float* __restrict__ u, float* __restrict__ v) {
  const int t = threadIdx.x;
  const int wave = t >> 6, lane = t & 63;
  const int r0 = blockIdx.x * 64;
  for (int rr = 0; rr < 16; ++rr) {
    const int row = r0 + wave * 16 + rr;
    const float* pe = h_eu + (size_t)row * DD;
    const float* pl = h_lo + (size_t)row * DD;
    const float* pp = h_po + (size_t)row * DD;
    float su = 0.f, sv = 0.f;
#pragma unroll
    for (int c = 0; c < 4; ++c) {
      const int d = lane + c * 64;
      su = fmaf(pe[d], a1[d], su);
      su = fmaf(pl[d], a3[d], su);
      sv = fmaf(pp[d], a2[d], sv);
    }
#pragma unroll
    for (int m = 32; m; m >>= 1) {
      su += __shfl_xor(su, m, 64);
      sv += __shfl_xor(sv, m, 64);
    }
    if (lane == 0) { u[row] = su * LOG2E; v[row] = sv * LOG2E; }
  }
}

// ---------------- prep: h_poT (bf16, [D][N]) ----------------
__global__ __launch_bounds__(256) void prep_T(
    const float* __restrict__ hpo, unsigned short* __restrict__ h_poT) {
  const int t = threadIdx.x;
  const int r0 = blockIdx.x * 64;
  unsigned short* dst = h_poT + (size_t)t * NN + r0;
#pragma unroll
  for (int c = 0; c < 16; ++c) {
    unsigned short x0 = f2bf(hpo[(size_t)(r0 + c * 4 + 0) * DD + t]);
    unsigned short x1 = f2bf(hpo[(size_t)(r0 + c * 4 + 1) * DD + t]);
    unsigned short x2 = f2bf(hpo[(size_t)(r0 + c * 4 + 2) * DD + t]);
    unsigned short x3 = f2bf(hpo[(size_t)(r0 + c * 4 + 3) * DD + t]);
    ((uint2*)dst)[c] = make_uint2((unsigned)x0 | ((unsigned)x1 << 16),
                                  (unsigned)x2 | ((unsigned)x3 << 16));
  }
}

// ---------------- fused12: producer/consumer wave specialization ------------
__global__ __launch_bounds__(1024) void fused12(
    const float* __restrict__ adj, const float* __restrict__ u2,
    const float* __restrict__ v2, const unsigned short* __restrict__ h_poT,
    float* __restrict__ out) {
  __shared__ __align__(16) char sMem[3 * BUFSZ];  // 135,936 B
  __shared__ float sq[2][3][16], sa[2][3][16];

  const int t = threadIdx.x;
  const int w = t >> 6, lane = t & 63;
  const int lrow = lane & 15, kgrp = lane >> 4;
  const int i0 = blockIdx.x * BM;

  if (w < 12) {
    // ======================= CONSUMERS (waves 0..11) =======================
    const int rg = w >> 2;           // 0..2 row-group
    const int dh = (w >> 1) & 1;     // 0..1 D-half
    const int kh = w & 1;            // 0..1 k-slice
    const int row = i0 + rg * 16 + lrow;
    const float u_r = u2[row];
    const float uc1 = u_r - SHIFT2;
    const float uc2 = fmaf(0.01f, u_r, -SHIFT2);
    const int xr = (lrow & 7) << 4;

    const int aOff = (rg * 16 + lrow) * 256;
    const int kA0 = (kh * 128 + kgrp * 32) ^ xr;
    const int kA1 = (kh * 128 + kgrp * 32 + 16) ^ xr;
    const int bOff = BOFF + (dh * 128 + lrow) * 128 + ((kh * 64 + kgrp * 16) ^ xr);
    const int vOff = VOFF + (kh * 32 + kgrp * 8) * 4;

    f32x4 acc1[8] = {};  // q   @ B
    f32x4 acc2[8] = {};  // adj @ B
    float qsum = 0.f, asum = 0.f;

    __syncthreads();  // prologue: producers staged bufs 0,1 (their drain)

    int buf = 0;
    for (int s = 0; s < NSTEPS; ++s) {
      const char* bufp = sMem + buf * BUFSZ;
      const f32x4 Vv0 = *(const f32x4*)(bufp + vOff);
      const f32x4 Vv1 = *(const f32x4*)(bufp + vOff + 16);
      const char* ab = bufp + aOff;
      const f32x4 A0 = *(const f32x4*)(ab + kA0);
      const f32x4 A1 = *(const f32x4*)(ab + kA1);
      const float af[8] = {A0[0], A0[1], A0[2], A0[3],
                           A1[0], A1[1], A1[2], A1[3]};
      const float vf[8] = {Vv0[0], Vv0[1], Vv0[2], Vv0[3],
                           Vv1[0], Vv1[1], Vv1[2], Vv1[3]};
      float qv[8];
#pragma unroll
      for (int e = 0; e < 8; ++e) {
        const float t1 = uc1 + vf[e];
        const float t2 = fmaf(0.01f, vf[e], uc2);
        float q = exp2_hw(fmaxf(t1, t2));
        q = (af[e] > 0.f) ? q : 0.f;
        qsum += q; asum += af[e]; qv[e] = q;
      }
      unsigned qp[4], ap[4];
#pragma unroll
      for (int e = 0; e < 4; ++e) {
        qp[e] = pack_bf2(qv[2 * e], qv[2 * e + 1]);
        ap[e] = pack_bf2(af[2 * e], af[2 * e + 1]);
      }
      const s16x8 qa = __builtin_bit_cast(s16x8, *(uint4*)qp);
      const s16x8 aa = __builtin_bit_cast(s16x8, *(uint4*)ap);
      const char* bb = bufp + bOff;
#pragma unroll
      for (int dt = 0; dt < 8; ++dt) {
        const s16x8 b = *(const s16x8*)(bb + dt * 2048);
        acc1[dt] = __builtin_amdgcn_mfma_f32_16x16x32_bf16(qa, b, acc1[dt], 0, 0, 0);
        acc2[dt] = __builtin_amdgcn_mfma_f32_16x16x32_bf16(aa, b, acc2[dt], 0, 0, 0);
      }
      __syncthreads();  // consumers: no outstanding vmem -> free wait
      buf = (buf == 2) ? 0 : buf + 1;
    }

    // ---- stats ----
    qsum += __shfl_xor(qsum, 16, 64); qsum += __shfl_xor(qsum, 32, 64);
    asum += __shfl_xor(asum, 16, 64); asum += __shfl_xor(asum, 32, 64);
    if (dh == 0 && lane < 16) { sq[kh][rg][lane] = qsum; sa[kh][rg][lane] = asum; }
    __syncthreads();

    // ---- fold coef, reduce over kh via LDS (reuse sMem), write out ----
    f32x4 fin[8];
#pragma unroll
    for (int dt = 0; dt < 8; ++dt) {
#pragma unroll
      for (int g = 0; g < 4; ++g) {
        const int rr = kgrp * 4 + g;
        const float qq = sq[0][rg][rr] + sq[1][rg][rr];
        const float aa2 = sa[0][rg][rr] + sa[1][rg][rr];
        const float cfr = qq > 0.f ? 0.5f * aa2 / qq : 0.f;
        fin[dt][g] = cfr * acc1[dt][g] + 0.5f * acc2[dt][g];
      }
    }
    float* red = (float*)sMem;  // 48 KB reduce area
    const int rbase = ((rg * 2 + dh) * 8 * 64 + lane) * 4;
    if (kh == 1) {
#pragma unroll
      for (int dt = 0; dt < 8; ++dt) *(f32x4*)&red[rbase + dt * 256] = fin[dt];
    }
    __syncthreads();
    if (kh == 0) {
#pragma unroll
      for (int dt = 0; dt < 8; ++dt) {
        const f32x4 o = *(const f32x4*)&red[rbase + dt * 256];
        const int col = dh * 128 + dt * 16 + lrow;
#pragma unroll
        for (int g = 0; g < 4; ++g)
          out[(size_t)(i0 + rg * 16 + kgrp * 4 + g) * DD + col] = fin[dt][g] + o[g];
      }
    }
  } else {
    // ======================= PRODUCERS (waves 12..15) ======================
    const int pid = w - 12;  // 0..3
    // 3 adj staging ops (fused9 formulas, idx = pid*3+j in 0..11)
    const char* pA[3];
    int dA[3];
#pragma unroll
    for (int j = 0; j < 3; ++j) {
      const int idx = pid * 3 + j;
      pA[j] = (const char*)(adj + (size_t)(i0 + idx * 4 + (lane >> 4)) * NN)
              + (((lane & 15) ^ ((idx & 1) * 4 + (lane >> 4))) << 4);
      dA[j] = idx * 1024;
    }
    // 8 B staging ops (ib = pid*8+j in 0..31)
    const int ko = ((lane & 7) ^ (lane >> 3)) << 4;
    const char* pB[8];
    int dB[8];
#pragma unroll
    for (int j = 0; j < 8; ++j) {
      const int ib = pid * 8 + j;
      pB[j] = (const char*)h_poT + (size_t)(ib * 8 + (lane >> 3)) * (NN * 2) + ko;
      dB[j] = BOFF + ib * 1024;
    }
    const float* pV = v2 + lane;
    const bool hasV = (pid == 3);

    // prologue: stage buffers 0 and 1 (steps 0,1)
#pragma unroll
    for (int b = 0; b < 2; ++b) {
      char* nb = sMem + b * BUFSZ;
#pragma unroll
      for (int j = 0; j < 3; ++j) { gl_lds16(pA[j], nb + dA[j]); pA[j] += 256; }
#pragma unroll
      for (int j = 0; j < 8; ++j) { gl_lds16(pB[j], nb + dB[j]); pB[j] += 128; }
      if (hasV) { gl_lds4(pV, nb + VOFF); pV += 64; }
    }
    __syncthreads();  // compiler drains vmcnt(0): bufs 0,1 resident

    int nbuf = 2;
    for (int s = 0; s < NSTEPS; ++s) {
      if (s < NSTEPS - 2) {
        char* nb = sMem + nbuf * BUFSZ;
#pragma unroll
        for (int j = 0; j < 3; ++j) { gl_lds16(pA[j], nb + dA[j]); pA[j] += 256; }
#pragma unroll
        for (int j = 0; j < 8; ++j) { gl_lds16(pB[j], nb + dB[j]); pB[j] += 128; }
        if (hasV) { gl_lds4(pV, nb + VOFF); pV += 64; }
      }
      __syncthreads();  // producer drain (vmcnt(0)) overlaps consumer compute
      nbuf = (nbuf == 2) ? 0 : nbuf + 1;
    }
    __syncthreads();  // match stats barrier
    __syncthreads();  // match reduce barrier
  }
}

// ---------------- fallback (small ws): round-2 proven kernel ----------------
__global__ __launch_bounds__(256) void fused_fb(
    const float* __restrict__ adj, const float* __restrict__ u,
    const float* __restrict__ v, const float* __restrict__ hpo,
    float* __restrict__ out) {
#define BMF 32
#define LDA 40
  __shared__ unsigned short qlds[BMF][LDA];
  __shared__ unsigned short alds[BMF][LDA];
  __shared__ unsigned short btf[DD][LDA];
  __shared__ float denom_s[BMF], deg_s[BMF], coef_s[BMF];

  const int t = threadIdx.x;
  const int wave = t >> 6, lane = t & 63;
  const int i0 = blockIdx.x * BMF;
  const int sr = t >> 3;
  const int sc = (t & 7) * 4;
  const float u_r = u[i0 + sr];
  const int d0 = wave * 64;
  const int lrow = lane & 15;
  const int kgrp = lane >> 4;

  f32x4 acc1[2][4] = {};
  f32x4 acc2[2][4] = {};
  float qsum = 0.f, asum = 0.f;

  const float* arow = adj + (size_t)(i0 + sr) * NN + sc;
  float4 a_cur = *(const float4*)(arow);

  constexpr int NSTEP = NN / 32;
  for (int jt = 0; jt < NSTEP; ++jt) {
    const int j = jt * 32;
    float4 a_nxt;
    const bool has_next = (jt + 1 < NSTEP);
    if (has_next) a_nxt = *(const float4*)(arow + j + 32);
    const float4 vv = *(const float4*)(v + j + sc);
    unsigned short qb[4], ab[4];
    {
      const float aa4[4] = {a_cur.x, a_cur.y, a_cur.z, a_cur.w};
      const float vvv[4] = {vv.x, vv.y, vv.z, vv.w};
#pragma unroll
      for (int k = 0; k < 4; ++k) {
        const float a = aa4[k];
        const float s = u_r + vvv[k];
        const float x = fmaxf(s, 0.01f * s);
        const float q = (a > 0.f) ? exp2_hw(x - SHIFT2) : 0.f;
        qsum += q;
        asum += a;
        qb[k] = f2bf(q);
        ab[k] = f2bf(a);
      }
    }
    *(uint2*)&qlds[sr][sc] = make_uint2((unsigned)qb[0] | ((unsigned)qb[1] << 16),
                                        (unsigned)qb[2] | ((unsigned)qb[3] << 16));
    *(uint2*)&alds[sr][sc] = make_uint2((unsigned)ab[0] | ((unsigned)ab[1] << 16),
                                        (unsigned)ab[2] | ((unsigned)ab[3] << 16));
    {
      const int br = t >> 3;
      const float* src = hpo + (size_t)(j + br) * DD;
#pragma unroll
      for (int cc = 0; cc < 8; ++cc) {
        const int c = (t & 7) * 4 + cc * 32;
        const float4 hv = *(const float4*)(src + c);
        btf[c + 0][br] = f2bf(hv.x);
        btf[c + 1][br] = f2bf(hv.y);
        btf[c + 2][br] = f2bf(hv.z);
        btf[c + 3][br] = f2bf(hv.w);
      }
    }
    __syncthreads();

    const s16x8 qa0 = *(const s16x8*)&qlds[lrow][kgrp * 8];
    const s16x8 qa1 = *(const s16x8*)&qlds[16 + lrow][kgrp * 8];
    const s16x8 ad0 = *(const s16x8*)&alds[lrow][kgrp * 8];
    const s16x8 ad1 = *(const s16x8*)&alds[16 + lrow][kgrp * 8];
#pragma unroll
    for (int dt = 0; dt < 4; ++dt) {
      const s16x8 b = *(const s16x8*)&btf[d0 + dt * 16 + lrow][kgrp * 8];
      acc1[0][dt] = __builtin_amdgcn_mfma_f32_16x16x32_bf16(qa0, b, acc1[0][dt], 0, 0, 0);
      acc1[1][dt] = __builtin_amdgcn_mfma_f32_16x16x32_bf16(qa1, b, acc1[1][dt], 0, 0, 0);
      acc2[0][dt] = __builtin_amdgcn_mfma_f32_16x16x32_bf16(ad0, b, acc2[0][dt], 0, 0, 0);
      acc2[1][dt] = __builtin_amdgcn_mfma_f32_16x16x32_bf16(ad1, b, acc2[1][dt], 0, 0, 0);
    }
    __syncthreads();
    if (has_next) a_cur = a_nxt;
  }
#pragma unroll
  for (int m = 1; m <= 4; m <<= 1) {
    qsum += __shfl_xor(qsum, m, 64);
    asum += __shfl_xor(asum, m, 64);
  }
  if ((t & 7) == 0) { denom_s[sr] = qsum; deg_s[sr] = asum; }
  __syncthreads();
  if (t < BMF) {
    const float dn = denom_s[t];
    coef_s[t] = dn > 0.f ? 0.5f * deg_s[t] / dn : 0.f;
  }
  __syncthreads();
#pragma unroll
  for (int f = 0; f < 2; ++f) {
#pragma unroll
    for (int dt = 0; dt < 4; ++dt) {
      const int col = d0 + dt * 16 + lrow;
#pragma unroll
      for (int g = 0; g < 4; ++g) {
        const int r = f * 16 + kgrp * 4 + g;
        out[(size_t)(i0 + r) * DD + col] =
            coef_s[r] * acc1[f][dt][g] + 0.5f * acc2[f][dt][g];
      }
    }
  }
}

extern "C" void kernel_launch(void* const* d_in, const int* in_sizes, int n_in,
                              void* d_out, int out_size, void* d_ws, size_t ws_size,
                              hipStream_t stream) {
  const float* h_eu = (const float*)d_in[0];
  const float* h_po = (const float*)d_in[1];
  const float* h_lo = (const float*)d_in[2];
  const float* adj  = (const float*)d_in[3];
  const float* a1   = (const float*)d_in[4];
  const float* a2   = (const float*)d_in[5];
  const float* a3   = (const float*)d_in[6];
  float* out = (float*)d_out;

  // ws layout: u[N] | v[N] | h_poT[D*N] bf16 = 6,389,760 B
  const size_t need_full = (size_t)2 * NN * 4 + (size_t)NN * DD * 2;
  float* u = (float*)d_ws;
  float* v = u + NN;
  unsigned short* h_poT = (unsigned short*)(v + NN);
  const bool big_ws = ws_size >= need_full;

  prep_uv<<<NN / 64, 256, 0, stream>>>(h_eu, h_po, h_lo, a1, a2, a3, u, v);
  if (big_ws) {
    prep_T<<<NN / 64, 256, 0, stream>>>(h_po, h_poT);
    fused12<<<NN / BM, 1024, 0, stream>>>(adj, u, v, h_poT, out);
  } else {
    fused_fb<<<NN / 32, 256, 0, stream>>>(adj, u, v, h_po, out);
  }
}

// Round 13
// 253.283 us; speedup vs baseline: 2.2893x; 1.2182x over previous
//
#include <hip/hip_runtime.h>
#include <hip/hip_bf16.h>

// N=12288, D=256. Single pass:
//   e=lrelu(u_i+v_j); q=exp2(e*log2e-SHIFT2) masked adj>0 (const shift, scale-free)
//   out_i = coef_i*(q_i@h_po) + 0.5*(adj_i@h_po),  coef_i=0.5*deg_i/denom_i
// fused13 = fused12 (producer/consumer wave specialization, 308us total) +
// counted vmcnt in the PRODUCER branch only:
//   - every producer wave issues a uniform 12 gl_lds per step (v loaded
//     redundantly by all 4 producers -> exact per-wave count)
//   - per step: issue s+2's 12 -> s_waitcnt vmcnt(12) (drains s+1's loads,
//     keeps s+2's in flight across the barrier; m135 in-order) -> s_barrier
//   - producer branch has ~30 live VGPRs: the fused8/11 spill mechanism
//     (asm pinning 128+ acc registers) structurally cannot fire here.
// Consumers byte-identical to fused12 (LDS-only loop, free barrier waits).

#define NN 12288
#define DD 256
#define BM 48
#define BK 64
#define NSTEPS (NN / BK)   // 192
#define BOFF 12288
#define VOFF 45056
#define BUFSZ 45312        // adj 12288 + B 32768 + v 256
#define LOG2E 1.44269504f
#define SHIFT2 36.067376f  // 25*log2e

typedef __attribute__((ext_vector_type(8))) short s16x8;
typedef __attribute__((ext_vector_type(4))) float f32x4;

__device__ __forceinline__ unsigned short f2bf(float f) {
  unsigned u = __builtin_bit_cast(unsigned, f);
  u += 0x7FFFu + ((u >> 16) & 1u);
  return (unsigned short)(u >> 16);
}
__device__ __forceinline__ unsigned pack_bf2(float a, float b) {
  unsigned short lo = __builtin_bit_cast(unsigned short, __float2bfloat16(a));
  unsigned short hi = __builtin_bit_cast(unsigned short, __float2bfloat16(b));
  return (unsigned)lo | ((unsigned)hi << 16);
}
__device__ __forceinline__ float exp2_hw(float x) {
  float r;
  asm("v_exp_f32 %0, %1" : "=v"(r) : "v"(x));
  return r;
}
__device__ __forceinline__ void gl_lds16(const void* g, void* l) {
  __builtin_amdgcn_global_load_lds(
      (const __attribute__((address_space(1))) void*)g,
      (__attribute__((address_space(3))) void*)l, 16, 0, 0);
}
__device__ __forceinline__ void gl_lds4(const void* g, void* l) {
  __builtin_amdgcn_global_load_lds(
      (const __attribute__((address_space(1))) void*)g,
      (__attribute__((address_space(3))) void*)l, 4, 0, 0);
}

// ---------------- prep: u2, v2 (pre-scaled by log2e) ----------------
__global__ __launch_bounds__(256) void prep_uv(
    const float* __restrict__ h_eu, const float* __restrict__ h_po,
    const float* __restrict__ h_lo, const float* __restrict__ a1,
    const float* __restrict__ a2, const float* __restrict__ a3,
    float* __restrict__ u, float* __restrict__ v) {
  const int t = threadIdx.x;
  const int wave = t >> 6, lane = t & 63;
  const int r0 = blockIdx.x * 64;
  for (int rr = 0; rr < 16; ++rr) {
    const int row = r0 + wave * 16 + rr;
    const float* pe = h_eu + (size_t)row * DD;
    const float* pl = h_lo + (size_t)row * DD;
    const float* pp = h_po + (size_t)row * DD;
    float su = 0.f, sv = 0.f;
#pragma unroll
    for (int c = 0; c < 4; ++c) {
      const int d = lane + c * 64;
      su = fmaf(pe[d], a1[d], su);
      su = fmaf(pl[d], a3[d], su);
      sv = fmaf(pp[d], a2[d], sv);
    }
#pragma unroll
    for (int m = 32; m; m >>= 1) {
      su += __shfl_xor(su, m, 64);
      sv += __shfl_xor(sv, m, 64);
    }
    if (lane == 0) { u[row] = su * LOG2E; v[row] = sv * LOG2E; }
  }
}

// ---------------- prep: h_poT (bf16, [D][N]) ----------------
__global__ __launch_bounds__(256) void prep_T(
    const float* __restrict__ hpo, unsigned short* __restrict__ h_poT) {
  const int t = threadIdx.x;
  const int r0 = blockIdx.x * 64;
  unsigned short* dst = h_poT + (size_t)t * NN + r0;
#pragma unroll
  for (int c = 0; c < 16; ++c) {
    unsigned short x0 = f2bf(hpo[(size_t)(r0 + c * 4 + 0) * DD + t]);
    unsigned short x1 = f2bf(hpo[(size_t)(r0 + c * 4 + 1) * DD + t]);
    unsigned short x2 = f2bf(hpo[(size_t)(r0 + c * 4 + 2) * DD + t]);
    unsigned short x3 = f2bf(hpo[(size_t)(r0 + c * 4 + 3) * DD + t]);
    ((uint2*)dst)[c] = make_uint2((unsigned)x0 | ((unsigned)x1 << 16),
                                  (unsigned)x2 | ((unsigned)x3 << 16));
  }
}

// ---------------- fused13: producer/consumer + counted producer waits -------
__global__ __launch_bounds__(1024) void fused13(
    const float* __restrict__ adj, const float* __restrict__ u2,
    const float* __restrict__ v2, const unsigned short* __restrict__ h_poT,
    float* __restrict__ out) {
  __shared__ __align__(16) char sMem[3 * BUFSZ];  // 135,936 B
  __shared__ float sq[2][3][16], sa[2][3][16];

  const int t = threadIdx.x;
  const int w = t >> 6, lane = t & 63;
  const int lrow = lane & 15, kgrp = lane >> 4;
  const int i0 = blockIdx.x * BM;

  if (w < 12) {
    // ======================= CONSUMERS (waves 0..11) =======================
    const int rg = w >> 2;           // 0..2 row-group
    const int dh = (w >> 1) & 1;     // 0..1 D-half
    const int kh = w & 1;            // 0..1 k-slice
    const int row = i0 + rg * 16 + lrow;
    const float u_r = u2[row];
    const float uc1 = u_r - SHIFT2;
    const float uc2 = fmaf(0.01f, u_r, -SHIFT2);
    const int xr = (lrow & 7) << 4;

    const int aOff = (rg * 16 + lrow) * 256;
    const int kA0 = (kh * 128 + kgrp * 32) ^ xr;
    const int kA1 = (kh * 128 + kgrp * 32 + 16) ^ xr;
    const int bOff = BOFF + (dh * 128 + lrow) * 128 + ((kh * 64 + kgrp * 16) ^ xr);
    const int vOff = VOFF + (kh * 32 + kgrp * 8) * 4;

    f32x4 acc1[8] = {};  // q   @ B
    f32x4 acc2[8] = {};  // adj @ B
    float qsum = 0.f, asum = 0.f;

    __syncthreads();  // prologue: producers staged bufs 0,1

    int buf = 0;
    for (int s = 0; s < NSTEPS; ++s) {
      const char* bufp = sMem + buf * BUFSZ;
      const f32x4 Vv0 = *(const f32x4*)(bufp + vOff);
      const f32x4 Vv1 = *(const f32x4*)(bufp + vOff + 16);
      const char* ab = bufp + aOff;
      const f32x4 A0 = *(const f32x4*)(ab + kA0);
      const f32x4 A1 = *(const f32x4*)(ab + kA1);
      const float af[8] = {A0[0], A0[1], A0[2], A0[3],
                           A1[0], A1[1], A1[2], A1[3]};
      const float vf[8] = {Vv0[0], Vv0[1], Vv0[2], Vv0[3],
                           Vv1[0], Vv1[1], Vv1[2], Vv1[3]};
      float qv[8];
#pragma unroll
      for (int e = 0; e < 8; ++e) {
        const float t1 = uc1 + vf[e];
        const float t2 = fmaf(0.01f, vf[e], uc2);
        float q = exp2_hw(fmaxf(t1, t2));
        q = (af[e] > 0.f) ? q : 0.f;
        qsum += q; asum += af[e]; qv[e] = q;
      }
      unsigned qp[4], ap[4];
#pragma unroll
      for (int e = 0; e < 4; ++e) {
        qp[e] = pack_bf2(qv[2 * e], qv[2 * e + 1]);
        ap[e] = pack_bf2(af[2 * e], af[2 * e + 1]);
      }
      const s16x8 qa = __builtin_bit_cast(s16x8, *(uint4*)qp);
      const s16x8 aa = __builtin_bit_cast(s16x8, *(uint4*)ap);
      const char* bb = bufp + bOff;
#pragma unroll
      for (int dt = 0; dt < 8; ++dt) {
        const s16x8 b = *(const s16x8*)(bb + dt * 2048);
        acc1[dt] = __builtin_amdgcn_mfma_f32_16x16x32_bf16(qa, b, acc1[dt], 0, 0, 0);
        acc2[dt] = __builtin_amdgcn_mfma_f32_16x16x32_bf16(aa, b, acc2[dt], 0, 0, 0);
      }
      __syncthreads();  // consumers: no outstanding vmem -> free wait
      buf = (buf == 2) ? 0 : buf + 1;
    }

    // ---- stats ----
    qsum += __shfl_xor(qsum, 16, 64); qsum += __shfl_xor(qsum, 32, 64);
    asum += __shfl_xor(asum, 16, 64); asum += __shfl_xor(asum, 32, 64);
    if (dh == 0 && lane < 16) { sq[kh][rg][lane] = qsum; sa[kh][rg][lane] = asum; }
    __syncthreads();

    // ---- fold coef, reduce over kh via LDS (reuse sMem), write out ----
    f32x4 fin[8];
#pragma unroll
    for (int dt = 0; dt < 8; ++dt) {
#pragma unroll
      for (int g = 0; g < 4; ++g) {
        const int rr = kgrp * 4 + g;
        const float qq = sq[0][rg][rr] + sq[1][rg][rr];
        const float aa2 = sa[0][rg][rr] + sa[1][rg][rr];
        const float cfr = qq > 0.f ? 0.5f * aa2 / qq : 0.f;
        fin[dt][g] = cfr * acc1[dt][g] + 0.5f * acc2[dt][g];
      }
    }
    float* red = (float*)sMem;  // 48 KB reduce area
    const int rbase = ((rg * 2 + dh) * 8 * 64 + lane) * 4;
    if (kh == 1) {
#pragma unroll
      for (int dt = 0; dt < 8; ++dt) *(f32x4*)&red[rbase + dt * 256] = fin[dt];
    }
    __syncthreads();
    if (kh == 0) {
#pragma unroll
      for (int dt = 0; dt < 8; ++dt) {
        const f32x4 o = *(const f32x4*)&red[rbase + dt * 256];
        const int col = dh * 128 + dt * 16 + lrow;
#pragma unroll
        for (int g = 0; g < 4; ++g)
          out[(size_t)(i0 + rg * 16 + kgrp * 4 + g) * DD + col] = fin[dt][g] + o[g];
      }
    }
  } else {
    // ======================= PRODUCERS (waves 12..15) ======================
    const int pid = w - 12;  // 0..3
    // 3 adj staging ops (idx = pid*3+j in 0..11)
    const char* pA[3];
    int dA[3];
#pragma unroll
    for (int j = 0; j < 3; ++j) {
      const int idx = pid * 3 + j;
      pA[j] = (const char*)(adj + (size_t)(i0 + idx * 4 + (lane >> 4)) * NN)
              + (((lane & 15) ^ ((idx & 1) * 4 + (lane >> 4))) << 4);
      dA[j] = idx * 1024;
    }
    // 8 B staging ops (ib = pid*8+j in 0..31)
    const int ko = ((lane & 7) ^ (lane >> 3)) << 4;
    const char* pB[8];
    int dB[8];
#pragma unroll
    for (int j = 0; j < 8; ++j) {
      const int ib = pid * 8 + j;
      pB[j] = (const char*)h_poT + (size_t)(ib * 8 + (lane >> 3)) * (NN * 2) + ko;
      dB[j] = BOFF + ib * 1024;
    }
    // v chunk: ALL producers load it (redundant same-byte LDS writes, benign)
    // -> uniform 12 vmem ops per wave per step, exact per-wave vmcnt count.
    const float* pV = v2 + lane;

    // prologue: stage buffers 0 and 1 (steps 0,1); keep buf1's 12 in flight
#pragma unroll
    for (int b = 0; b < 2; ++b) {
      char* nb = sMem + b * BUFSZ;
#pragma unroll
      for (int j = 0; j < 3; ++j) { gl_lds16(pA[j], nb + dA[j]); pA[j] += 256; }
#pragma unroll
      for (int j = 0; j < 8; ++j) { gl_lds16(pB[j], nb + dB[j]); pB[j] += 128; }
      gl_lds4(pV, nb + VOFF); pV += 64;
    }
    asm volatile("s_waitcnt vmcnt(12)" ::: "memory");  // buf0 resident
    __builtin_amdgcn_s_barrier();

    int nbuf = 2;
    for (int s = 0; s < NSTEPS; ++s) {
      if (s < NSTEPS - 2) {
        char* nb = sMem + nbuf * BUFSZ;
#pragma unroll
        for (int j = 0; j < 3; ++j) { gl_lds16(pA[j], nb + dA[j]); pA[j] += 256; }
#pragma unroll
        for (int j = 0; j < 8; ++j) { gl_lds16(pB[j], nb + dB[j]); pB[j] += 128; }
        gl_lds4(pV, nb + VOFF); pV += 64;
        // drain step-(s+1)'s 12 loads; keep this step's 12 in flight
        asm volatile("s_waitcnt vmcnt(12)" ::: "memory");
      } else if (s == NSTEPS - 2) {
        asm volatile("s_waitcnt vmcnt(0)" ::: "memory");  // final buf resident
      }
      __builtin_amdgcn_s_barrier();
      nbuf = (nbuf == 2) ? 0 : nbuf + 1;
    }
    __syncthreads();  // match stats barrier
    __syncthreads();  // match reduce barrier
  }
}

// ---------------- fallback (small ws): round-2 proven kernel ----------------
__global__ __launch_bounds__(256) void fused_fb(
    const float* __restrict__ adj, const float* __restrict__ u,
    const float* __restrict__ v, const float* __restrict__ hpo,
    float* __restrict__ out) {
#define BMF 32
#define LDA 40
  __shared__ unsigned short qlds[BMF][LDA];
  __shared__ unsigned short alds[BMF][LDA];
  __shared__ unsigned short btf[DD][LDA];
  __shared__ float denom_s[BMF], deg_s[BMF], coef_s[BMF];

  const int t = threadIdx.x;
  const int wave = t >> 6, lane = t & 63;
  const int i0 = blockIdx.x * BMF;
  const int sr = t >> 3;
  const int sc = (t & 7) * 4;
  const float u_r = u[i0 + sr];
  const int d0 = wave * 64;
  const int lrow = lane & 15;
  const int kgrp = lane >> 4;

  f32x4 acc1[2][4] = {};
  f32x4 acc2[2][4] = {};
  float qsum = 0.f, asum = 0.f;

  const float* arow = adj + (size_t)(i0 + sr) * NN + sc;
  float4 a_cur = *(const float4*)(arow);

  constexpr int NSTEP = NN / 32;
  for (int jt = 0; jt < NSTEP; ++jt) {
    const int j = jt * 32;
    float4 a_nxt;
    const bool has_next = (jt + 1 < NSTEP);
    if (has_next) a_nxt = *(const float4*)(arow + j + 32);
    const float4 vv = *(const float4*)(v + j + sc);
    unsigned short qb[4], ab[4];
    {
      const float aa4[4] = {a_cur.x, a_cur.y, a_cur.z, a_cur.w};
      const float vvv[4] = {vv.x, vv.y, vv.z, vv.w};
#pragma unroll
      for (int k = 0; k < 4; ++k) {
        const float a = aa4[k];
        const float s = u_r + vvv[k];
        const float x = fmaxf(s, 0.01f * s);
        const float q = (a > 0.f) ? exp2_hw(x - SHIFT2) : 0.f;
        qsum += q;
        asum += a;
        qb[k] = f2bf(q);
        ab[k] = f2bf(a);
      }
    }
    *(uint2*)&qlds[sr][sc] = make_uint2((unsigned)qb[0] | ((unsigned)qb[1] << 16),
                                        (unsigned)qb[2] | ((unsigned)qb[3] << 16));
    *(uint2*)&alds[sr][sc] = make_uint2((unsigned)ab[0] | ((unsigned)ab[1] << 16),
                                        (unsigned)ab[2] | ((unsigned)ab[3] << 16));
    {
      const int br = t >> 3;
      const float* src = hpo + (size_t)(j + br) * DD;
#pragma unroll
      for (int cc = 0; cc < 8; ++cc) {
        const int c = (t & 7) * 4 + cc * 32;
        const float4 hv = *(const float4*)(src + c);
        btf[c + 0][br] = f2bf(hv.x);
        btf[c + 1][br] = f2bf(hv.y);
        btf[c + 2][br] = f2bf(hv.z);
        btf[c + 3][br] = f2bf(hv.w);
      }
    }
    __syncthreads();

    const s16x8 qa0 = *(const s16x8*)&qlds[lrow][kgrp * 8];
    const s16x8 qa1 = *(const s16x8*)&qlds[16 + lrow][kgrp * 8];
    const s16x8 ad0 = *(const s16x8*)&alds[lrow][kgrp * 8];
    const s16x8 ad1 = *(const s16x8*)&alds[16 + lrow][kgrp * 8];
#pragma unroll
    for (int dt = 0; dt < 4; ++dt) {
      const s16x8 b = *(const s16x8*)&btf[d0 + dt * 16 + lrow][kgrp * 8];
      acc1[0][dt] = __builtin_amdgcn_mfma_f32_16x16x32_bf16(qa0, b, acc1[0][dt], 0, 0, 0);
      acc1[1][dt] = __builtin_amdgcn_mfma_f32_16x16x32_bf16(qa1, b, acc1[1][dt], 0, 0, 0);
      acc2[0][dt] = __builtin_amdgcn_mfma_f32_16x16x32_bf16(ad0, b, acc2[0][dt], 0, 0, 0);
      acc2[1][dt] = __builtin_amdgcn_mfma_f32_16x16x32_bf16(ad1, b, acc2[1][dt], 0, 0, 0);
    }
    __syncthreads();
    if (has_next) a_cur = a_nxt;
  }
#pragma unroll
  for (int m = 1; m <= 4; m <<= 1) {
    qsum += __shfl_xor(qsum, m, 64);
    asum += __shfl_xor(asum, m, 64);
  }
  if ((t & 7) == 0) { denom_s[sr] = qsum; deg_s[sr] = asum; }
  __syncthreads();
  if (t < BMF) {
    const float dn = denom_s[t];
    coef_s[t] = dn > 0.f ? 0.5f * deg_s[t] / dn : 0.f;
  }
  __syncthreads();
#pragma unroll
  for (int f = 0; f < 2; ++f) {
#pragma unroll
    for (int dt = 0; dt < 4; ++dt) {
      const int col = d0 + dt * 16 + lrow;
#pragma unroll
      for (int g = 0; g < 4; ++g) {
        const int r = f * 16 + kgrp * 4 + g;
        out[(size_t)(i0 + r) * DD + col] =
            coef_s[r] * acc1[f][dt][g] + 0.5f * acc2[f][dt][g];
      }
    }
  }
}

extern "C" void kernel_launch(void* const* d_in, const int* in_sizes, int n_in,
                              void* d_out, int out_size, void* d_ws, size_t ws_size,
                              hipStream_t stream) {
  const float* h_eu = (const float*)d_in[0];
  const float* h_po = (const float*)d_in[1];
  const float* h_lo = (const float*)d_in[2];
  const float* adj  = (const float*)d_in[3];
  const float* a1   = (const float*)d_in[4];
  const float* a2   = (const float*)d_in[5];
  const float* a3   = (const float*)d_in[6];
  float* out = (float*)d_out;

  // ws layout: u[N] | v[N] | h_poT[D*N] bf16 = 6,389,760 B
  const size_t need_full = (size_t)2 * NN * 4 + (size_t)NN * DD * 2;
  float* u = (float*)d_ws;
  float* v = u + NN;
  unsigned short* h_poT = (unsigned short*)(v + NN);
  const bool big_ws = ws_size >= need_full;

  prep_uv<<<NN / 64, 256, 0, stream>>>(h_eu, h_po, h_lo, a1, a2, a3, u, v);
  if (big_ws) {
    prep_T<<<NN / 64, 256, 0, stream>>>(h_po, h_poT);
    fused13<<<NN / BM, 1024, 0, stream>>>(adj, u, v, h_poT, out);
  } else {
    fused_fb<<<NN / 32, 256, 0, stream>>>(adj, u, v, h_po, out);
  }
}